// Round 6
// baseline (179.662 us; speedup 1.0000x reference)
//
#include <hip/hip_runtime.h>

// VQ-VAE VectorQuantizer2: z [4,8,64,64] f32, emb [16384,8] f32
// outputs: z_q [4,8,64,64] f32 | loss [1] f32 | idx [16384] written as f32
//
// R6 architecture: MFMA filter + exact f32 rescan.
//  - d_k = fl(Zn - fl(2*dot_k)) is MONOTONE in dot_k, so the argmin winners all
//    satisfy dot_k >= max_dot - q/2 (q = ulp of d near Zn).
//  - bf16 two-term split (z=z_hi+z_lo, e=e_hi+e_lo) packed into K=32:
//    A=[z_hi,z_lo,z_hi,z_lo], B=[e_hi,e_lo,e_lo,e_hi] -> one
//    mfma_f32_16x16x32_bf16 gives s~ = z.e with |err| <= ~2e-8.
//  - Online per-row running-max threshold (max - W) collects a guaranteed
//    SUPERSET of winners (W = Zn*2.5e-7 + 5e-7 >> q/2 + 2*err).
//  - Finalize: exact sequential-fma chain (R1-proven numerics) on candidates,
//    lexicographic (dd_bits, k) min == first-index argmin. Overflowed lists
//    fall back to exact scan of that split range (correct by construction).

typedef short bf16x8 __attribute__((ext_vector_type(8)));
typedef float f32x4  __attribute__((ext_vector_type(4)));

#define N_ROW 16384
#define N_E   16384
#define HW    4096
#define NSPL  8
#define SPLIT (N_E / NSPL)      // 2048 codes per split
#define CHK   256               // codes per LDS stage
#define NCHK  (SPLIT / CHK)     // 8
#define CAP   24                // candidate slots per (row, split)

static __device__ __forceinline__ unsigned short bf16_rne(float x) {
    unsigned u = __float_as_uint(x);
    unsigned r = (u >> 16) & 1u;
    return (unsigned short)((u + 0x7FFFu + r) >> 16);
}

// ---------------- prep: split z and emb into bf16 hi/lo, compute Zn and W ----
// pe[k][16] = [e_hi(8), e_lo(8)] bf16 ; pz[n][16] = [z_hi(8), z_lo(8)] bf16
__global__ __launch_bounds__(256) void vq_prep(const float* __restrict__ z,
                                               const float* __restrict__ emb,
                                               unsigned short* __restrict__ pe,
                                               unsigned short* __restrict__ pz,
                                               float* __restrict__ Zn_arr,
                                               float* __restrict__ W_arr) {
    const int t = blockIdx.x * 256 + threadIdx.x;   // 0..32767
    __align__(16) unsigned short o16[16];
    if (t < N_E) {
        const float* e = emb + (size_t)t * 8;
        float v[8];
#pragma unroll
        for (int c = 0; c < 8; ++c) v[c] = e[c];
#pragma unroll
        for (int c = 0; c < 8; ++c) {
            unsigned short hb = bf16_rne(v[c]);
            float hf = __uint_as_float((unsigned)hb << 16);
            float lo = v[c] - hf;                   // Sterbenz-exact residual
            o16[c] = hb; o16[8 + c] = bf16_rne(lo);
        }
        uint4* d = (uint4*)(pe + (size_t)t * 16);
        const uint4* s = (const uint4*)o16;
        d[0] = s[0]; d[1] = s[1];
    } else {
        const int n = t - N_E;
        const int b = n >> 12, hw = n & 4095;
        const float* zp = z + (size_t)b * 32768 + hw;
        float v[8];
#pragma unroll
        for (int c = 0; c < 8; ++c) v[c] = zp[c * HW];
        // Zn = sequential f32 sum of squares, NO fma contraction (numerics contract)
        float Zn;
        {
#pragma clang fp contract(off)
            Zn = v[0] * v[0];
#pragma unroll
            for (int c = 1; c < 8; ++c) { float q = v[c] * v[c]; Zn = Zn + q; }
        }
#pragma unroll
        for (int c = 0; c < 8; ++c) {
            unsigned short hb = bf16_rne(v[c]);
            float hf = __uint_as_float((unsigned)hb << 16);
            float lo = v[c] - hf;
            o16[c] = hb; o16[8 + c] = bf16_rne(lo);
        }
        uint4* d = (uint4*)(pz + (size_t)n * 16);
        const uint4* s = (const uint4*)o16;
        d[0] = s[0]; d[1] = s[1];
        Zn_arr[n] = Zn;
        // W = q/2 + MFMA-err slack, generous 2x: covers ulp(d) over adjacent binades
        W_arr[n] = __builtin_fmaf(Zn, 2.5e-7f, 5e-7f);
    }
}

// ---------------- MFMA scan: collect candidate superset per (row, split) ----
__global__ __launch_bounds__(256) void vq_scanA(const unsigned short* __restrict__ pe,
                                                const unsigned short* __restrict__ pz,
                                                const float* __restrict__ Wr,
                                                unsigned short* __restrict__ lists,
                                                unsigned short* __restrict__ cnts) {
    __shared__ __align__(16) unsigned short se[CHK * 16];  // 8 KB staged codes
    __shared__ unsigned scnt[64];
    const int tid = threadIdx.x;
    const int wid = tid >> 6, lane = tid & 63;
    const int rowbase = (blockIdx.x >> 3) * 64;            // 64 rows per block
    const int split = blockIdx.x & 7;
    if (tid < 64) scnt[tid] = 0u;

    const int col = lane & 15;
    const int g = lane >> 4;
    const int sel8 = (g == 1 || g == 2) ? 8 : 0;           // B k-octet: hi,lo,lo,hi
    // A-frag (16x16x32 bf16, m89-verified): row = lane&15, k-octet = lane>>4
    // packed A = [z_hi, z_lo, z_hi, z_lo] -> octet (g&1)
    const int arow = rowbase + wid * 16 + col;
    const bf16x8 afrag = *(const bf16x8*)(pz + (size_t)arow * 16 + (g & 1) * 8);
    // C-frag rows: growbase + r  (col = lane&15)
    const int growbase = rowbase + wid * 16 + g * 4;
    float W4[4], rmax[4], thr[4];
#pragma unroll
    for (int r = 0; r < 4; ++r) { W4[r] = Wr[growbase + r]; rmax[r] = -3.4e38f; thr[r] = 3.4e38f; }
    const f32x4 zero4 = {0.f, 0.f, 0.f, 0.f};
    const size_t cbase0 = (size_t)split * SPLIT;

    for (int chk = 0; chk < NCHK; ++chk) {
        __syncthreads();
        {   // stage 256 codes x 32 B
            const uint4* src = (const uint4*)(pe + (cbase0 + (size_t)chk * CHK) * 16);
            uint4* dst = (uint4*)se;
            dst[tid] = src[tid];
            dst[tid + 256] = src[tid + 256];
        }
        __syncthreads();
        if (chk == 0) {
            // tile-0 max-only pass to initialize the threshold (prevents first-tile flood)
            const bf16x8 bfrag = *(const bf16x8*)(se + col * 16 + sel8);
            f32x4 cc = __builtin_amdgcn_mfma_f32_16x16x32_bf16(afrag, bfrag, zero4, 0, 0, 0);
#pragma unroll
            for (int r = 0; r < 4; ++r) {
                float m = fmaxf(rmax[r], cc[r]);
                m = fmaxf(m, __shfl_xor(m, 1)); m = fmaxf(m, __shfl_xor(m, 2));
                m = fmaxf(m, __shfl_xor(m, 4)); m = fmaxf(m, __shfl_xor(m, 8));
                rmax[r] = m; thr[r] = m - W4[r];
            }
        }
#pragma unroll 4
        for (int t = 0; t < CHK / 16; ++t) {
            const bf16x8 bfrag = *(const bf16x8*)(se + (t * 16 + col) * 16 + sel8);
            f32x4 cc = __builtin_amdgcn_mfma_f32_16x16x32_bf16(afrag, bfrag, zero4, 0, 0, 0);
            const int kcode = (int)cbase0 + chk * CHK + t * 16 + col;
            bool hh[4];
#pragma unroll
            for (int r = 0; r < 4; ++r) { hh[r] = (cc[r] >= thr[r]); rmax[r] = fmaxf(rmax[r], cc[r]); }
            if (__any(hh[0] | hh[1] | hh[2] | hh[3])) {
#pragma unroll
                for (int r = 0; r < 4; ++r) {
                    if (hh[r]) {
                        unsigned p = atomicAdd(&scnt[wid * 16 + g * 4 + r], 1u);
                        if (p < CAP)
                            lists[((size_t)(growbase + r) * NSPL + split) * CAP + p] = (unsigned short)kcode;
                    }
                }
            }
            if (t & 1) {   // refresh group max + threshold every 2 tiles (stale thr => superset, safe)
#pragma unroll
                for (int r = 0; r < 4; ++r) {
                    float m = rmax[r];
                    m = fmaxf(m, __shfl_xor(m, 1)); m = fmaxf(m, __shfl_xor(m, 2));
                    m = fmaxf(m, __shfl_xor(m, 4)); m = fmaxf(m, __shfl_xor(m, 8));
                    rmax[r] = m; thr[r] = m - W4[r];
                }
            }
        }
    }
    __syncthreads();
    if (tid < 64) {
        unsigned c = scnt[tid];
        cnts[(size_t)(rowbase + tid) * NSPL + split] = (unsigned short)(c > 65535u ? 65535u : c);
    }
}

// ---------------- finalize: exact rescan of candidates, emit outputs --------
__global__ __launch_bounds__(256) void vq_fin(const float* __restrict__ z,
                                              const float* __restrict__ emb,
                                              const unsigned short* __restrict__ lists,
                                              const unsigned short* __restrict__ cnts,
                                              const float* __restrict__ Zn_arr,
                                              float* __restrict__ out_zq,
                                              float* __restrict__ out_idx,
                                              double* __restrict__ acc) {
    __shared__ float lsum[4];
    const int tid = threadIdx.x, wid = tid >> 6, lane = tid & 63;
    const int row = blockIdx.x * 4 + wid;      // one wave per row
    const int b = row >> 12, hw = row & 4095;
    float zv[8];
#pragma unroll
    for (int c = 0; c < 8; ++c) zv[c] = z[(size_t)b * 32768 + (size_t)c * 4096 + hw];
    const float Zn = Zn_arr[row];

    int cn[8];
    {
        const uint4 cw = *(const uint4*)(cnts + (size_t)row * 8);
        cn[0] = cw.x & 0xFFFF; cn[1] = cw.x >> 16; cn[2] = cw.y & 0xFFFF; cn[3] = cw.y >> 16;
        cn[4] = cw.z & 0xFFFF; cn[5] = cw.z >> 16; cn[6] = cw.w & 0xFFFF; cn[7] = cw.w >> 16;
    }
    int base_s[8]; int total = 0;
#pragma unroll
    for (int s = 0; s < 8; ++s) { base_s[s] = total; total += (cn[s] > CAP ? CAP : cn[s]); }

    unsigned long long best = ~0ull;
    for (int j = lane; j < total; j += 64) {
        int s = 7;
#pragma unroll
        for (int q = 6; q >= 0; --q) if (j < base_s[q + 1]) s = q;
        const int k = lists[((size_t)row * NSPL + s) * CAP + (j - base_s[s])];
        const float* e = emb + (size_t)k * 8;
        float dot = zv[0] * e[0];
#pragma unroll
        for (int c = 1; c < 8; ++c) dot = __builtin_fmaf(zv[c], e[c], dot);
        const float dd = __builtin_fmaf(-2.f, dot, Zn);
        unsigned u = __float_as_uint(dd);
        unsigned m = (u & 0x80000000u) ? ~u : (u | 0x80000000u);   // monotone total order
        unsigned long long key = ((unsigned long long)m << 32) | (unsigned)k;
        if (key < best) best = key;
    }
    // overflowed splits: exact scan of the whole split range (rare, correct)
#pragma unroll
    for (int s = 0; s < 8; ++s) {
        if (cn[s] > CAP) {
            for (int k = s * SPLIT + lane; k < (s + 1) * SPLIT; k += 64) {
                const float* e = emb + (size_t)k * 8;
                float dot = zv[0] * e[0];
#pragma unroll
                for (int c = 1; c < 8; ++c) dot = __builtin_fmaf(zv[c], e[c], dot);
                const float dd = __builtin_fmaf(-2.f, dot, Zn);
                unsigned u = __float_as_uint(dd);
                unsigned m2 = (u & 0x80000000u) ? ~u : (u | 0x80000000u);
                unsigned long long key = ((unsigned long long)m2 << 32) | (unsigned)k;
                if (key < best) best = key;
            }
        }
    }
#pragma unroll
    for (int off = 32; off > 0; off >>= 1) {
        unsigned long long o = __shfl_xor(best, off);
        if (o < best) best = o;
    }
    const int kstar = (int)(unsigned)(best & 0xFFFFFFFFull);
    if (lane == 0) out_idx[row] = (float)kstar;
    float sl = 0.f;
    if (lane < 8) {
        const float ev = emb[(size_t)kstar * 8 + lane];
        out_zq[(size_t)b * 32768 + (size_t)lane * 4096 + hw] = ev;
        const float df = ev - zv[lane];
        sl = df * df;
    }
    sl += __shfl_xor(sl, 1); sl += __shfl_xor(sl, 2); sl += __shfl_xor(sl, 4);
    if (lane == 0) lsum[wid] = sl;
    __syncthreads();
    if (tid == 0) {
        double tloss = (double)lsum[0] + (double)lsum[1] + (double)lsum[2] + (double)lsum[3];
        atomicAdd(acc, tloss);
    }
}

// ---------------- finalize loss ----------------
__global__ void vq_final(const double* __restrict__ acc, float* __restrict__ out_loss) {
    double m = acc[0] / (double)(N_ROW * 8);
    float mf = (float)m;
    out_loss[0] = mf + 0.25f * mf;   // fwd values of the two loss terms are equal
}

extern "C" void kernel_launch(void* const* d_in, const int* in_sizes, int n_in,
                              void* d_out, int out_size, void* d_ws, size_t ws_size,
                              hipStream_t stream) {
    const float* z   = (const float*)d_in[0];
    const float* emb = (const float*)d_in[1];

    float* out      = (float*)d_out;
    float* out_zq   = out;               // 131072
    float* out_loss = out + 131072;      // 1
    float* out_idx  = out + 131073;      // 16384

    // ws layout (~7.4 MB; R2 proved ws >= 8.4 MB):
    char* w = (char*)d_ws;
    double*         acc  = (double*)w;                     w += 64;
    float*          Zn   = (float*)w;                      w += (size_t)N_ROW * 4;
    float*          Wr   = (float*)w;                      w += (size_t)N_ROW * 4;
    unsigned short* pz   = (unsigned short*)w;             w += (size_t)N_ROW * 32;
    unsigned short* pe   = (unsigned short*)w;             w += (size_t)N_E * 32;
    unsigned short* cnts = (unsigned short*)w;             w += (size_t)N_ROW * NSPL * 2;
    unsigned short* lists = (unsigned short*)w;

    hipMemsetAsync(d_ws, 0, 64, stream);
    vq_prep <<<dim3(128),  dim3(256), 0, stream>>>(z, emb, pe, pz, Zn, Wr);
    vq_scanA<<<dim3((N_ROW / 64) * NSPL), dim3(256), 0, stream>>>(pe, pz, Wr, lists, cnts);
    vq_fin  <<<dim3(N_ROW / 4), dim3(256), 0, stream>>>(z, emb, lists, cnts, Zn, out_zq, out_idx, acc);
    vq_final<<<dim3(1), dim3(1), 0, stream>>>(acc, out_loss);
}

// Round 7
// 143.013 us; speedup vs baseline: 1.2563x; 1.2563x over previous
//
#include <hip/hip_runtime.h>

// VQ-VAE VectorQuantizer2: z [4,8,64,64] f32, emb [16384,8] f32
// outputs: z_q [4,8,64,64] f32 | loss [1] f32 | idx [16384] written as f32
//
// R7 architecture: 2-pass MFMA filter + exact f32 rescan.
//  - d_k = fl(Zn - fl(2*dot_k)) is MONOTONE in dot_k -> winners satisfy
//    dot_k >= max_dot - q/2 (q = ulp of d near Zn).
//  - bf16 two-term split packed into K=32: A=[z_hi,z_lo,z_hi,z_lo],
//    B=[e_hi,e_lo,e_lo,e_hi] -> one mfma_f32_16x16x32_bf16 = z.e exactly
//    to ~1e-9 (all 4 cross products present).
//  - Pass 1: per-row EXACT max of approx-dot (per-lane fmax only; one
//    cross-lane reduce at the end — R6's per-2-tile shfl refresh was 60% of
//    its runtime). Pass 2: recompute + collect superset with thr = max - W,
//    W = Zn*2.5e-7 + 5e-7 >= 2x (q/2 + 2*eps)  [R6-proven with a LOOSER thr].
//  - Finalize: exact sequential-fma chain on candidates, lexicographic
//    (dd_bits, k) min == first-index argmin; overflowed splits -> exact scan.

typedef short bf16x8 __attribute__((ext_vector_type(8)));
typedef float f32x4  __attribute__((ext_vector_type(4)));

#define N_ROW 16384
#define N_E   16384
#define HW    4096
#define NSPL  8
#define SPLIT (N_E / NSPL)     // 2048 codes per split
#define HALF  1024             // codes staged per LDS fill
#define CAP   24               // candidate slots per (row, split)

static __device__ __forceinline__ unsigned short bf16_rne(float x) {
    unsigned u = __float_as_uint(x);
    unsigned r = (u >> 16) & 1u;
    return (unsigned short)((u + 0x7FFFu + r) >> 16);
}

// ---------------- prep (z-side only): bf16 hi/lo split + Zn ----------------
__global__ __launch_bounds__(256) void vq_prep(const float* __restrict__ z,
                                               unsigned short* __restrict__ pz,
                                               float* __restrict__ Zn_arr) {
    const int n = blockIdx.x * 256 + threadIdx.x;       // 0..16383
    const int b = n >> 12, hw = n & 4095;
    const float* zp = z + (size_t)b * 32768 + hw;
    float v[8];
#pragma unroll
    for (int c = 0; c < 8; ++c) v[c] = zp[c * HW];
    float Zn;
    {   // sequential f32 sum of squares, NO fma contraction (numerics contract)
#pragma clang fp contract(off)
        Zn = v[0] * v[0];
#pragma unroll
        for (int c = 1; c < 8; ++c) { float q = v[c] * v[c]; Zn = Zn + q; }
    }
    unsigned hb[8], lb[8];
#pragma unroll
    for (int c = 0; c < 8; ++c) {
        hb[c] = bf16_rne(v[c]);
        float hf = __uint_as_float(hb[c] << 16);
        lb[c] = bf16_rne(v[c] - hf);                    // residual is Sterbenz-exact
    }
    uint4 uh, ul;
    uh.x = hb[0] | (hb[1] << 16); uh.y = hb[2] | (hb[3] << 16);
    uh.z = hb[4] | (hb[5] << 16); uh.w = hb[6] | (hb[7] << 16);
    ul.x = lb[0] | (lb[1] << 16); ul.y = lb[2] | (lb[3] << 16);
    ul.z = lb[4] | (lb[5] << 16); ul.w = lb[6] | (lb[7] << 16);
    ((uint4*)pz)[(size_t)n * 2]     = uh;               // [hi octet | lo octet]
    ((uint4*)pz)[(size_t)n * 2 + 1] = ul;
    Zn_arr[n] = Zn;
}

// ---------------- 2-pass MFMA scan ----------------
__global__ __launch_bounds__(256, 4) void vq_scanA(const float* __restrict__ emb,
                                                   const unsigned short* __restrict__ pz,
                                                   const float* __restrict__ Zn_arr,
                                                   unsigned short* __restrict__ lists,
                                                   unsigned short* __restrict__ cnts) {
    __shared__ __align__(16) unsigned short se_hi[HALF * 8];   // 16 KB
    __shared__ __align__(16) unsigned short se_lo[HALF * 8];   // 16 KB
    __shared__ unsigned scnt[256];

    const int tid = threadIdx.x, wid = tid >> 6, lane = tid & 63;
    const int rowbase = (int)(blockIdx.x >> 3) * 256;   // 256 rows per block
    const int split = blockIdx.x & 7;
    const int col = lane & 15, g = lane >> 4;
    const bool lo_sel = (g == 1 || g == 2);             // B k-octets: hi,lo,lo,hi
    const unsigned short* seB = lo_sel ? se_lo : se_hi;

    // A-frags: wave owns 64 rows = 4 x 16; A k-octets [hi,lo,hi,lo] -> (g&1)
    bf16x8 afrag[4];
#pragma unroll
    for (int a = 0; a < 4; ++a)
        afrag[a] = *(const bf16x8*)(pz + (size_t)(rowbase + wid * 64 + a * 16 + col) * 16 + (g & 1) * 8);

    const f32x4 zero4 = {0.f, 0.f, 0.f, 0.f};
    const float* esplit = emb + (size_t)split * SPLIT * 8;

    float rmax[4][4];
#pragma unroll
    for (int a = 0; a < 4; ++a)
#pragma unroll
        for (int r = 0; r < 4; ++r) rmax[a][r] = -3.4e38f;

    // ---- pass 1: exact per-row max of approx dot ----
    for (int half = 0; half < 2; ++half) {
        __syncthreads();
        // stage 1024 codes: f32 -> bf16 hi/lo, 4 codes/thread
#pragma unroll
        for (int j = 0; j < 4; ++j) {
            const int code = tid + j * 256;
            const float4 va = ((const float4*)esplit)[(size_t)(half * HALF + code) * 2];
            const float4 vb = ((const float4*)esplit)[(size_t)(half * HALF + code) * 2 + 1];
            const float v[8] = {va.x, va.y, va.z, va.w, vb.x, vb.y, vb.z, vb.w};
            unsigned hb[8], lb[8];
#pragma unroll
            for (int c = 0; c < 8; ++c) {
                hb[c] = bf16_rne(v[c]);
                float hf = __uint_as_float(hb[c] << 16);
                lb[c] = bf16_rne(v[c] - hf);
            }
            uint4 uh, ul;
            uh.x = hb[0] | (hb[1] << 16); uh.y = hb[2] | (hb[3] << 16);
            uh.z = hb[4] | (hb[5] << 16); uh.w = hb[6] | (hb[7] << 16);
            ul.x = lb[0] | (lb[1] << 16); ul.y = lb[2] | (lb[3] << 16);
            ul.z = lb[4] | (lb[5] << 16); ul.w = lb[6] | (lb[7] << 16);
            ((uint4*)se_hi)[code] = uh;
            ((uint4*)se_lo)[code] = ul;
        }
        __syncthreads();
#pragma unroll 4
        for (int t = 0; t < HALF / 16; ++t) {
            const bf16x8 bfrag = *(const bf16x8*)(seB + (size_t)(t * 16 + col) * 8);
            f32x4 cc[4];
            cc[0] = __builtin_amdgcn_mfma_f32_16x16x32_bf16(afrag[0], bfrag, zero4, 0, 0, 0);
            cc[1] = __builtin_amdgcn_mfma_f32_16x16x32_bf16(afrag[1], bfrag, zero4, 0, 0, 0);
            cc[2] = __builtin_amdgcn_mfma_f32_16x16x32_bf16(afrag[2], bfrag, zero4, 0, 0, 0);
            cc[3] = __builtin_amdgcn_mfma_f32_16x16x32_bf16(afrag[3], bfrag, zero4, 0, 0, 0);
#pragma unroll
            for (int a = 0; a < 4; ++a)
#pragma unroll
                for (int r = 0; r < 4; ++r) rmax[a][r] = fmaxf(rmax[a][r], cc[a][r]);
        }
    }

    // one cross-lane reduce (16 col-lanes share each row) + threshold
    float thr[4][4];
#pragma unroll
    for (int a = 0; a < 4; ++a)
#pragma unroll
        for (int r = 0; r < 4; ++r) {
            float m = rmax[a][r];
            m = fmaxf(m, __shfl_xor(m, 1));
            m = fmaxf(m, __shfl_xor(m, 2));
            m = fmaxf(m, __shfl_xor(m, 4));
            m = fmaxf(m, __shfl_xor(m, 8));
            const float Zn = Zn_arr[rowbase + wid * 64 + a * 16 + g * 4 + r];
            thr[a][r] = m - __builtin_fmaf(Zn, 2.5e-7f, 5e-7f);
        }
    scnt[tid] = 0u;

    // ---- pass 2: recompute + collect candidate superset ----
    for (int half = 0; half < 2; ++half) {
        __syncthreads();
#pragma unroll
        for (int j = 0; j < 4; ++j) {
            const int code = tid + j * 256;
            const float4 va = ((const float4*)esplit)[(size_t)(half * HALF + code) * 2];
            const float4 vb = ((const float4*)esplit)[(size_t)(half * HALF + code) * 2 + 1];
            const float v[8] = {va.x, va.y, va.z, va.w, vb.x, vb.y, vb.z, vb.w};
            unsigned hb[8], lb[8];
#pragma unroll
            for (int c = 0; c < 8; ++c) {
                hb[c] = bf16_rne(v[c]);
                float hf = __uint_as_float(hb[c] << 16);
                lb[c] = bf16_rne(v[c] - hf);
            }
            uint4 uh, ul;
            uh.x = hb[0] | (hb[1] << 16); uh.y = hb[2] | (hb[3] << 16);
            uh.z = hb[4] | (hb[5] << 16); uh.w = hb[6] | (hb[7] << 16);
            ul.x = lb[0] | (lb[1] << 16); ul.y = lb[2] | (lb[3] << 16);
            ul.z = lb[4] | (lb[5] << 16); ul.w = lb[6] | (lb[7] << 16);
            ((uint4*)se_hi)[code] = uh;
            ((uint4*)se_lo)[code] = ul;
        }
        __syncthreads();
#pragma unroll 2
        for (int t = 0; t < HALF / 16; ++t) {
            const bf16x8 bfrag = *(const bf16x8*)(seB + (size_t)(t * 16 + col) * 8);
            f32x4 cc[4];
            cc[0] = __builtin_amdgcn_mfma_f32_16x16x32_bf16(afrag[0], bfrag, zero4, 0, 0, 0);
            cc[1] = __builtin_amdgcn_mfma_f32_16x16x32_bf16(afrag[1], bfrag, zero4, 0, 0, 0);
            cc[2] = __builtin_amdgcn_mfma_f32_16x16x32_bf16(afrag[2], bfrag, zero4, 0, 0, 0);
            cc[3] = __builtin_amdgcn_mfma_f32_16x16x32_bf16(afrag[3], bfrag, zero4, 0, 0, 0);
            const int kcode = split * SPLIT + half * HALF + t * 16 + col;
            bool anyh = false;
#pragma unroll
            for (int a = 0; a < 4; ++a)
#pragma unroll
                for (int r = 0; r < 4; ++r) anyh |= (cc[a][r] >= thr[a][r]);
            if (__any(anyh)) {
#pragma unroll
                for (int a = 0; a < 4; ++a)
#pragma unroll
                    for (int r = 0; r < 4; ++r)
                        if (cc[a][r] >= thr[a][r]) {
                            const int lr = wid * 64 + a * 16 + g * 4 + r;
                            unsigned p = atomicAdd(&scnt[lr], 1u);
                            if (p < CAP)
                                lists[((size_t)(rowbase + lr) * NSPL + split) * CAP + p] = (unsigned short)kcode;
                        }
            }
        }
    }
    __syncthreads();
    {
        unsigned c = scnt[tid];
        cnts[(size_t)(rowbase + tid) * NSPL + split] = (unsigned short)(c > 65535u ? 65535u : c);
    }
}

// ---------------- finalize: exact rescan of candidates (R6-proven) ----------
__global__ __launch_bounds__(256) void vq_fin(const float* __restrict__ z,
                                              const float* __restrict__ emb,
                                              const unsigned short* __restrict__ lists,
                                              const unsigned short* __restrict__ cnts,
                                              const float* __restrict__ Zn_arr,
                                              float* __restrict__ out_zq,
                                              float* __restrict__ out_idx,
                                              double* __restrict__ acc) {
    __shared__ float lsum[4];
    const int tid = threadIdx.x, wid = tid >> 6, lane = tid & 63;
    const int row = blockIdx.x * 4 + wid;      // one wave per row
    const int b = row >> 12, hw = row & 4095;
    float zv[8];
#pragma unroll
    for (int c = 0; c < 8; ++c) zv[c] = z[(size_t)b * 32768 + (size_t)c * 4096 + hw];
    const float Zn = Zn_arr[row];

    int cn[8];
    {
        const uint4 cw = *(const uint4*)(cnts + (size_t)row * 8);
        cn[0] = cw.x & 0xFFFF; cn[1] = cw.x >> 16; cn[2] = cw.y & 0xFFFF; cn[3] = cw.y >> 16;
        cn[4] = cw.z & 0xFFFF; cn[5] = cw.z >> 16; cn[6] = cw.w & 0xFFFF; cn[7] = cw.w >> 16;
    }
    int base_s[8]; int total = 0;
#pragma unroll
    for (int s = 0; s < 8; ++s) { base_s[s] = total; total += (cn[s] > CAP ? CAP : cn[s]); }

    unsigned long long best = ~0ull;
    for (int j = lane; j < total; j += 64) {
        int s = 7;
#pragma unroll
        for (int q = 6; q >= 0; --q) if (j < base_s[q + 1]) s = q;
        const int k = lists[((size_t)row * NSPL + s) * CAP + (j - base_s[s])];
        const float* e = emb + (size_t)k * 8;
        float dot = zv[0] * e[0];
#pragma unroll
        for (int c = 1; c < 8; ++c) dot = __builtin_fmaf(zv[c], e[c], dot);
        const float dd = __builtin_fmaf(-2.f, dot, Zn);
        unsigned u = __float_as_uint(dd);
        unsigned m = (u & 0x80000000u) ? ~u : (u | 0x80000000u);   // monotone total order
        unsigned long long key = ((unsigned long long)m << 32) | (unsigned)k;
        if (key < best) best = key;
    }
    // overflowed splits: exact scan of the whole split range (rare, correct)
#pragma unroll
    for (int s = 0; s < 8; ++s) {
        if (cn[s] > CAP) {
            for (int k = s * SPLIT + lane; k < (s + 1) * SPLIT; k += 64) {
                const float* e = emb + (size_t)k * 8;
                float dot = zv[0] * e[0];
#pragma unroll
                for (int c = 1; c < 8; ++c) dot = __builtin_fmaf(zv[c], e[c], dot);
                const float dd = __builtin_fmaf(-2.f, dot, Zn);
                unsigned u = __float_as_uint(dd);
                unsigned m2 = (u & 0x80000000u) ? ~u : (u | 0x80000000u);
                unsigned long long key = ((unsigned long long)m2 << 32) | (unsigned)k;
                if (key < best) best = key;
            }
        }
    }
#pragma unroll
    for (int off = 32; off > 0; off >>= 1) {
        unsigned long long o = __shfl_xor(best, off);
        if (o < best) best = o;
    }
    const int kstar = (int)(unsigned)(best & 0xFFFFFFFFull);
    if (lane == 0) out_idx[row] = (float)kstar;
    float sl = 0.f;
    if (lane < 8) {
        const float ev = emb[(size_t)kstar * 8 + lane];
        out_zq[(size_t)b * 32768 + (size_t)lane * 4096 + hw] = ev;
        const float df = ev - zv[lane];
        sl = df * df;
    }
    sl += __shfl_xor(sl, 1); sl += __shfl_xor(sl, 2); sl += __shfl_xor(sl, 4);
    if (lane == 0) lsum[wid] = sl;
    __syncthreads();
    if (tid == 0) {
        double tloss = (double)lsum[0] + (double)lsum[1] + (double)lsum[2] + (double)lsum[3];
        atomicAdd(acc, tloss);
    }
}

// ---------------- finalize loss ----------------
__global__ void vq_final(const double* __restrict__ acc, float* __restrict__ out_loss) {
    double m = acc[0] / (double)(N_ROW * 8);
    float mf = (float)m;
    out_loss[0] = mf + 0.25f * mf;   // fwd values of the two loss terms are equal
}

extern "C" void kernel_launch(void* const* d_in, const int* in_sizes, int n_in,
                              void* d_out, int out_size, void* d_ws, size_t ws_size,
                              hipStream_t stream) {
    const float* z   = (const float*)d_in[0];
    const float* emb = (const float*)d_in[1];

    float* out      = (float*)d_out;
    float* out_zq   = out;               // 131072
    float* out_loss = out + 131072;      // 1
    float* out_idx  = out + 131073;      // 16384

    // ws layout (~7.2 MB; R2 proved ws >= 8.4 MB):
    char* w = (char*)d_ws;
    double*         acc   = (double*)w;            w += 64;
    float*          Zn    = (float*)w;             w += (size_t)N_ROW * 4;
    unsigned short* pz    = (unsigned short*)w;    w += (size_t)N_ROW * 32;
    unsigned short* cnts  = (unsigned short*)w;    w += (size_t)N_ROW * NSPL * 2;
    unsigned short* lists = (unsigned short*)w;

    hipMemsetAsync(d_ws, 0, 64, stream);
    vq_prep <<<dim3(64),   dim3(256), 0, stream>>>(z, pz, Zn);
    vq_scanA<<<dim3((N_ROW / 256) * NSPL), dim3(256), 0, stream>>>(emb, pz, Zn, lists, cnts);
    vq_fin  <<<dim3(N_ROW / 4), dim3(256), 0, stream>>>(z, emb, lists, cnts, Zn, out_zq, out_idx, acc);
    vq_final<<<dim3(1), dim3(1), 0, stream>>>(acc, out_loss);
}

// Round 8
// 92.844 us; speedup vs baseline: 1.9351x; 1.5404x over previous
//
#include <hip/hip_runtime.h>

// VQ-VAE VectorQuantizer2: z [4,8,64,64] f32, emb [16384,8] f32
// outputs: z_q [4,8,64,64] f32 | loss [1] f32 | idx [16384] written as f32
//
// R8 architecture: 2-kernel MFMA filter (global threshold) + exact rescan.
//  - d_k = fl(Zn - fl(2*dot_k)) MONOTONE in dot_k -> winners satisfy
//    dot_k >= gmax - q/2 (q = ulp of d near Zn).
//  - bf16 two-term split packed into K=32: A=[z_hi,z_lo,z_hi,z_lo],
//    B=[e_hi,e_lo,e_lo,e_hi] -> mfma_f32_16x16x32_bf16 = z.e to ~2e-9.
//  - vq_maxk: per-(row,split) max of approx dot (per-lane fmax only, one
//    cross-lane reduce). vq_coll: GLOBAL thr = max_s(maxs) - W,
//    W = Zn*2.5e-7 + 5e-7 >= 2x(q/2 + 2eps) [R6/R7-proven], append
//    candidate superset via device-scope atomics into one per-row list.
//  - vq_fin: exact sequential-fma chain on candidates (16 lanes/row),
//    lexicographic (dd_bits, k) min == first-index argmin; cnt>CAP ->
//    exact full-row scan (correct regardless of list contents).

typedef short bf16x8 __attribute__((ext_vector_type(8)));
typedef float f32x4  __attribute__((ext_vector_type(4)));

#define N_ROW 16384
#define N_E   16384
#define NSPL  16
#define SPLIT (N_E / NSPL)     // 1024 codes per split
#define TILES (SPLIT / 16)     // 64
#define CAP   64               // candidate slots per row (global list)

static __device__ __forceinline__ unsigned short bf16_rne(float x) {
    unsigned u = __float_as_uint(x);
    unsigned r = (u >> 16) & 1u;
    return (unsigned short)((u + 0x7FFFu + r) >> 16);
}

// ---------------- prep (z-side): bf16 hi/lo split + Zn ----------------
__global__ __launch_bounds__(256) void vq_prep(const float* __restrict__ z,
                                               unsigned short* __restrict__ pz,
                                               float* __restrict__ Zn_arr) {
    const int n = blockIdx.x * 256 + threadIdx.x;       // 0..16383
    const int b = n >> 12, hw = n & 4095;
    const float* zp = z + (size_t)b * 32768 + hw;
    float v[8];
#pragma unroll
    for (int c = 0; c < 8; ++c) v[c] = zp[c * 4096];
    float Zn;
    {   // sequential f32 sum of squares, NO fma contraction (numerics contract)
#pragma clang fp contract(off)
        Zn = v[0] * v[0];
#pragma unroll
        for (int c = 1; c < 8; ++c) { float q = v[c] * v[c]; Zn = Zn + q; }
    }
    unsigned hb[8], lb[8];
#pragma unroll
    for (int c = 0; c < 8; ++c) {
        hb[c] = bf16_rne(v[c]);
        float hf = __uint_as_float(hb[c] << 16);
        lb[c] = bf16_rne(v[c] - hf);                    // residual Sterbenz-exact
    }
    uint4 uh, ul;
    uh.x = hb[0] | (hb[1] << 16); uh.y = hb[2] | (hb[3] << 16);
    uh.z = hb[4] | (hb[5] << 16); uh.w = hb[6] | (hb[7] << 16);
    ul.x = lb[0] | (lb[1] << 16); ul.y = lb[2] | (lb[3] << 16);
    ul.z = lb[4] | (lb[5] << 16); ul.w = lb[6] | (lb[7] << 16);
    ((uint4*)pz)[(size_t)n * 2]     = uh;               // [hi octet | lo octet]
    ((uint4*)pz)[(size_t)n * 2 + 1] = ul;
    Zn_arr[n] = Zn;
}

// common staging: 1024 codes f32 -> bf16 hi/lo into LDS (4 codes/thread)
static __device__ __forceinline__ void stage_codes(const float* __restrict__ esplit,
                                                   unsigned short* se_hi,
                                                   unsigned short* se_lo,
                                                   int tid) {
#pragma unroll
    for (int j = 0; j < 4; ++j) {
        const int code = tid + j * 256;
        const float4 va = ((const float4*)esplit)[(size_t)code * 2];
        const float4 vb = ((const float4*)esplit)[(size_t)code * 2 + 1];
        const float v[8] = {va.x, va.y, va.z, va.w, vb.x, vb.y, vb.z, vb.w};
        unsigned hb[8], lb[8];
#pragma unroll
        for (int c = 0; c < 8; ++c) {
            hb[c] = bf16_rne(v[c]);
            float hf = __uint_as_float(hb[c] << 16);
            lb[c] = bf16_rne(v[c] - hf);
        }
        uint4 uh, ul;
        uh.x = hb[0] | (hb[1] << 16); uh.y = hb[2] | (hb[3] << 16);
        uh.z = hb[4] | (hb[5] << 16); uh.w = hb[6] | (hb[7] << 16);
        ul.x = lb[0] | (lb[1] << 16); ul.y = lb[2] | (lb[3] << 16);
        ul.z = lb[4] | (lb[5] << 16); ul.w = lb[6] | (lb[7] << 16);
        ((uint4*)se_hi)[code] = uh;
        ((uint4*)se_lo)[code] = ul;
    }
}

// ---------------- pass 1 kernel: per-(row,split) max of approx dot ----------
__global__ __launch_bounds__(256, 4) void vq_maxk(const float* __restrict__ emb,
                                                  const unsigned short* __restrict__ pz,
                                                  float* __restrict__ maxs) {
    __shared__ __align__(16) unsigned short se_hi[SPLIT * 8];   // 16 KB
    __shared__ __align__(16) unsigned short se_lo[SPLIT * 8];   // 16 KB
    const int tid = threadIdx.x, wid = tid >> 6, lane = tid & 63;
    const int rowbase = (int)(blockIdx.x >> 4) * 256;
    const int split = blockIdx.x & 15;
    const int col = lane & 15, g = lane >> 4;
    const unsigned short* seB = (g == 1 || g == 2) ? se_lo : se_hi;  // B: hi,lo,lo,hi

    bf16x8 afrag[4];                                    // A: [hi,lo,hi,lo] -> (g&1)
#pragma unroll
    for (int a = 0; a < 4; ++a)
        afrag[a] = *(const bf16x8*)(pz + (size_t)(rowbase + wid * 64 + a * 16 + col) * 16 + (g & 1) * 8);

    stage_codes(emb + (size_t)split * SPLIT * 8, se_hi, se_lo, tid);
    __syncthreads();

    const f32x4 zero4 = {0.f, 0.f, 0.f, 0.f};
    float rmax[4][4];
#pragma unroll
    for (int a = 0; a < 4; ++a)
#pragma unroll
        for (int r = 0; r < 4; ++r) rmax[a][r] = -3.4e38f;

#pragma unroll 2
    for (int t = 0; t < TILES; ++t) {
        const bf16x8 bfrag = *(const bf16x8*)(seB + (size_t)(t * 16 + col) * 8);
        f32x4 cc[4];
        cc[0] = __builtin_amdgcn_mfma_f32_16x16x32_bf16(afrag[0], bfrag, zero4, 0, 0, 0);
        cc[1] = __builtin_amdgcn_mfma_f32_16x16x32_bf16(afrag[1], bfrag, zero4, 0, 0, 0);
        cc[2] = __builtin_amdgcn_mfma_f32_16x16x32_bf16(afrag[2], bfrag, zero4, 0, 0, 0);
        cc[3] = __builtin_amdgcn_mfma_f32_16x16x32_bf16(afrag[3], bfrag, zero4, 0, 0, 0);
#pragma unroll
        for (int a = 0; a < 4; ++a)
#pragma unroll
            for (int r = 0; r < 4; ++r) rmax[a][r] = fmaxf(rmax[a][r], cc[a][r]);
    }
    // one cross-lane reduce over the 16 code-columns
#pragma unroll
    for (int a = 0; a < 4; ++a)
#pragma unroll
        for (int r = 0; r < 4; ++r) {
            float m = rmax[a][r];
            m = fmaxf(m, __shfl_xor(m, 1));
            m = fmaxf(m, __shfl_xor(m, 2));
            m = fmaxf(m, __shfl_xor(m, 4));
            m = fmaxf(m, __shfl_xor(m, 8));
            if (col == 0)
                maxs[(size_t)(rowbase + wid * 64 + a * 16 + g * 4 + r) * NSPL + split] = m;
        }
}

// ---------------- pass 2 kernel: collect superset with GLOBAL threshold ----
__global__ __launch_bounds__(256, 4) void vq_coll(const float* __restrict__ emb,
                                                  const unsigned short* __restrict__ pz,
                                                  const float* __restrict__ Zn_arr,
                                                  const float* __restrict__ maxs,
                                                  unsigned short* __restrict__ lists,
                                                  unsigned* __restrict__ cnt) {
    __shared__ __align__(16) unsigned short se_hi[SPLIT * 8];
    __shared__ __align__(16) unsigned short se_lo[SPLIT * 8];
    __shared__ float sthr[256];
    const int tid = threadIdx.x, wid = tid >> 6, lane = tid & 63;
    const int rowbase = (int)(blockIdx.x >> 4) * 256;
    const int split = blockIdx.x & 15;
    const int col = lane & 15, g = lane >> 4;
    const unsigned short* seB = (g == 1 || g == 2) ? se_lo : se_hi;

    bf16x8 afrag[4];
#pragma unroll
    for (int a = 0; a < 4; ++a)
        afrag[a] = *(const bf16x8*)(pz + (size_t)(rowbase + wid * 64 + a * 16 + col) * 16 + (g & 1) * 8);

    {   // global per-row threshold: gmax over splits - W   (coalesced float4 x4)
        const int row = rowbase + tid;
        const float4* mp = (const float4*)(maxs + (size_t)row * NSPL);
        const float4 a4 = mp[0], b4 = mp[1], c4 = mp[2], d4 = mp[3];
        float m = fmaxf(fmaxf(fmaxf(a4.x, a4.y), fmaxf(a4.z, a4.w)),
                        fmaxf(fmaxf(b4.x, b4.y), fmaxf(b4.z, b4.w)));
        m = fmaxf(m, fmaxf(fmaxf(fmaxf(c4.x, c4.y), fmaxf(c4.z, c4.w)),
                           fmaxf(fmaxf(d4.x, d4.y), fmaxf(d4.z, d4.w))));
        sthr[tid] = m - __builtin_fmaf(Zn_arr[row], 2.5e-7f, 5e-7f);
    }
    stage_codes(emb + (size_t)split * SPLIT * 8, se_hi, se_lo, tid);
    __syncthreads();

    float thr[4][4];
#pragma unroll
    for (int a = 0; a < 4; ++a)
#pragma unroll
        for (int r = 0; r < 4; ++r) thr[a][r] = sthr[wid * 64 + a * 16 + g * 4 + r];

    const f32x4 zero4 = {0.f, 0.f, 0.f, 0.f};
#pragma unroll 2
    for (int t = 0; t < TILES; ++t) {
        const bf16x8 bfrag = *(const bf16x8*)(seB + (size_t)(t * 16 + col) * 8);
        f32x4 cc[4];
        cc[0] = __builtin_amdgcn_mfma_f32_16x16x32_bf16(afrag[0], bfrag, zero4, 0, 0, 0);
        cc[1] = __builtin_amdgcn_mfma_f32_16x16x32_bf16(afrag[1], bfrag, zero4, 0, 0, 0);
        cc[2] = __builtin_amdgcn_mfma_f32_16x16x32_bf16(afrag[2], bfrag, zero4, 0, 0, 0);
        cc[3] = __builtin_amdgcn_mfma_f32_16x16x32_bf16(afrag[3], bfrag, zero4, 0, 0, 0);
        bool anyh = false;
#pragma unroll
        for (int a = 0; a < 4; ++a)
#pragma unroll
            for (int r = 0; r < 4; ++r) anyh |= (cc[a][r] >= thr[a][r]);
        if (__any(anyh)) {
            const int kcode = split * SPLIT + t * 16 + col;
#pragma unroll
            for (int a = 0; a < 4; ++a)
#pragma unroll
                for (int r = 0; r < 4; ++r)
                    if (cc[a][r] >= thr[a][r]) {
                        const int row = rowbase + wid * 64 + a * 16 + g * 4 + r;
                        unsigned p = atomicAdd(&cnt[row], 1u);   // device-scope
                        if (p < CAP) lists[(size_t)row * CAP + p] = (unsigned short)kcode;
                    }
        }
    }
}

// ---------------- finalize: exact rescan, 16 lanes per row ----------------
__global__ __launch_bounds__(256) void vq_fin(const float* __restrict__ z,
                                              const float* __restrict__ emb,
                                              const unsigned short* __restrict__ lists,
                                              const unsigned* __restrict__ cnt,
                                              const float* __restrict__ Zn_arr,
                                              float* __restrict__ out_zq,
                                              float* __restrict__ out_idx,
                                              double* __restrict__ acc) {
    __shared__ float lsum[4];
    const int tid = threadIdx.x, wid = tid >> 6, lane = tid & 63;
    const int sub = lane >> 4, c16 = lane & 15;
    const int row = blockIdx.x * 16 + wid * 4 + sub;    // grid 1024 -> all 16384 rows
    const int b = row >> 12, hw = row & 4095;
    float zv[8];
#pragma unroll
    for (int c = 0; c < 8; ++c) zv[c] = z[(size_t)b * 32768 + (size_t)c * 4096 + hw];
    const float Zn = Zn_arr[row];
    const unsigned n = cnt[row];

    unsigned long long best = ~0ull;
    if (n <= CAP) {
        for (unsigned j = c16; j < n; j += 16) {
            const int k = lists[(size_t)row * CAP + j];
            const float* e = emb + (size_t)k * 8;
            float dot = zv[0] * e[0];
#pragma unroll
            for (int c = 1; c < 8; ++c) dot = __builtin_fmaf(zv[c], e[c], dot);
            const float dd = __builtin_fmaf(-2.f, dot, Zn);
            unsigned u = __float_as_uint(dd);
            unsigned m = (u & 0x80000000u) ? ~u : (u | 0x80000000u);  // monotone order
            unsigned long long key = ((unsigned long long)m << 32) | (unsigned)k;
            if (key < best) best = key;
        }
    } else {
        for (int k = c16; k < N_E; k += 16) {           // overflow: exact full scan
            const float* e = emb + (size_t)k * 8;
            float dot = zv[0] * e[0];
#pragma unroll
            for (int c = 1; c < 8; ++c) dot = __builtin_fmaf(zv[c], e[c], dot);
            const float dd = __builtin_fmaf(-2.f, dot, Zn);
            unsigned u = __float_as_uint(dd);
            unsigned m = (u & 0x80000000u) ? ~u : (u | 0x80000000u);
            unsigned long long key = ((unsigned long long)m << 32) | (unsigned)k;
            if (key < best) best = key;
        }
    }
#pragma unroll
    for (int off = 1; off < 16; off <<= 1) {            // reduce within 16-lane group
        unsigned long long o = __shfl_xor(best, off);
        if (o < best) best = o;
    }
    const int kstar = (int)(unsigned)(best & 0xFFFFFFFFull);
    if (c16 == 0) out_idx[row] = (float)kstar;
    float sl = 0.f;
    if (c16 < 8) {
        const float ev = emb[(size_t)kstar * 8 + c16];
        out_zq[(size_t)b * 32768 + (size_t)c16 * 4096 + hw] = ev;
        const float df = ev - zv[c16];
        sl = df * df;
    }
    sl += __shfl_xor(sl, 1); sl += __shfl_xor(sl, 2); sl += __shfl_xor(sl, 4);
    float rowsum = (c16 == 0) ? sl : 0.f;
    rowsum += __shfl_xor(rowsum, 16);
    rowsum += __shfl_xor(rowsum, 32);                   // all lanes: sum of wave's 4 rows
    if (lane == 0) lsum[wid] = rowsum;
    __syncthreads();
    if (tid == 0) {
        double t = (double)lsum[0] + (double)lsum[1] + (double)lsum[2] + (double)lsum[3];
        atomicAdd(acc, t);
    }
}

// ---------------- finalize loss ----------------
__global__ void vq_final(const double* __restrict__ acc, float* __restrict__ out_loss) {
    double m = acc[0] / (double)(N_ROW * 8);
    float mf = (float)m;
    out_loss[0] = mf + 0.25f * mf;   // fwd values of the two loss terms are equal
}

extern "C" void kernel_launch(void* const* d_in, const int* in_sizes, int n_in,
                              void* d_out, int out_size, void* d_ws, size_t ws_size,
                              hipStream_t stream) {
    const float* z   = (const float*)d_in[0];
    const float* emb = (const float*)d_in[1];

    float* out      = (float*)d_out;
    float* out_zq   = out;               // 131072
    float* out_loss = out + 131072;      // 1
    float* out_idx  = out + 131073;      // 16384

    // ws layout (~3.7 MB; R2 proved ws >= 8.4 MB):
    char* w = (char*)d_ws;
    double*         acc   = (double*)w;            w += 64;
    unsigned*       cnt   = (unsigned*)w;          w += (size_t)N_ROW * 4;
    float*          Zn    = (float*)w;             w += (size_t)N_ROW * 4;
    unsigned short* pz    = (unsigned short*)w;    w += (size_t)N_ROW * 32;
    float*          maxs  = (float*)w;             w += (size_t)N_ROW * NSPL * 4;
    unsigned short* lists = (unsigned short*)w;

    hipMemsetAsync(d_ws, 0, 64 + (size_t)N_ROW * 4, stream);   // acc + cnt
    vq_prep <<<dim3(64),   dim3(256), 0, stream>>>(z, pz, Zn);
    vq_maxk <<<dim3((N_ROW / 256) * NSPL), dim3(256), 0, stream>>>(emb, pz, maxs);
    vq_coll <<<dim3((N_ROW / 256) * NSPL), dim3(256), 0, stream>>>(emb, pz, Zn, maxs, lists, cnt);
    vq_fin  <<<dim3(N_ROW / 16), dim3(256), 0, stream>>>(z, emb, lists, cnt, Zn, out_zq, out_idx, acc);
    vq_final<<<dim3(1), dim3(1), 0, stream>>>(acc, out_loss);
}